// Round 9
// baseline (206.781 us; speedup 1.0000x reference)
//
#include <hip/hip_runtime.h>

// Centroid update: per-class mean of embed rows, blended with old centroid.
//   sums[c,:] = sum_{i: y[i]==c} embed[i,:]
//   out[c,:]  = 0.3 * sums[c,:]/count[c] + 0.7 * centroid[c,:]
//
// v9 = v8 (201.2 µs, best) + two within-wave serialization fixes:
//  1. T14 async-split of the scan: v8 issued SCAN(k+1) BEFORE the gather,
//     so each wave stalled on y's L2 latency (~250 cyc) before issuing any
//     gather loads, every chunk. Now chunk k+1's y-labels are LOADED into
//     registers early (prev iteration) and the compare/LDS-atomic CLASSIFY
//     runs AFTER chunk k's gather — y latency hides under the whole gather
//     phase. Per-chunk counters nm[8] (zeroed once, never reset) keep this
//     at ONE barrier per chunk with no reset-ordering hazard.
//  2. Gather bursts 4 -> 8 deep (16 VGPRs of float2 in flight, no spill):
//     ~4 KB outstanding per wave during gather.
// Kept from v8: 2000 blocks (class x dim-half, float2/thread, 8 B/lane),
// ~31 waves/CU ceiling; embed read exactly once device-wide (disjoint
// 2 KB halves of each 4 KB row); y scan L2-served.

#define BATCH       32768
#define EMBED_DIM   1024
#define NUM_CLASSES 1000
#define FACTOR      0.3f
#define HALF_DIM    512
#define CHUNK       4096   // labels per chunk; 16 per thread as 4 x int4
#define NCHUNK      (BATCH / CHUNK)
#define MAXR        80     // per-chunk matches: Poisson(4.1), max ~20; 80 safe

__global__ __launch_bounds__(256) void centroid_kernel(
    const float* __restrict__ embed,
    const int*   __restrict__ y,
    const float* __restrict__ centroid,
    float*       __restrict__ out)
{
    const int bid = blockIdx.x;
    const int c   = bid >> 1;                 // class
    const int h   = bid & 1;                  // dim half
    const int tid = threadIdx.x;
    const int d0  = h * HALF_DIM + tid * 2;   // this thread's 2 dims

    __shared__ int rows[2][MAXR];             // double-buffered match lists
    __shared__ int nm[NCHUNK];                // per-chunk counters (no resets)

    if (tid < NCHUNK) nm[tid] = 0;

    // Hoisted: centroid load overlaps everything.
    const size_t o = (size_t)c * EMBED_DIM + d0;
    const float2 cen = *reinterpret_cast<const float2*>(centroid + o);

    __syncthreads();

    // ---- Prologue: classify chunk 0 directly into rows[0]; stage chunk 1's
    // labels into registers (consumed after chunk 0's gather).
    {
        const int base_ = tid * 4;
        #pragma unroll
        for (int q = 0; q < 4; ++q) {
            const int idx = base_ + q * 1024;
            const int4 v = *reinterpret_cast<const int4*>(y + idx);
            if (v.x == c) { int p = atomicAdd(&nm[0], 1); rows[0][p] = idx + 0; }
            if (v.y == c) { int p = atomicAdd(&nm[0], 1); rows[0][p] = idx + 1; }
            if (v.z == c) { int p = atomicAdd(&nm[0], 1); rows[0][p] = idx + 2; }
            if (v.w == c) { int p = atomicAdd(&nm[0], 1); rows[0][p] = idx + 3; }
        }
    }
    int4 yv0, yv1, yv2, yv3;                  // staged labels (chunk k+1)
    {
        const int base_ = CHUNK + tid * 4;
        yv0 = *reinterpret_cast<const int4*>(y + base_ + 0 * 1024);
        yv1 = *reinterpret_cast<const int4*>(y + base_ + 1 * 1024);
        yv2 = *reinterpret_cast<const int4*>(y + base_ + 2 * 1024);
        yv3 = *reinterpret_cast<const int4*>(y + base_ + 3 * 1024);
    }
    __syncthreads();

    float2 accs[4];
    #pragma unroll
    for (int a = 0; a < 4; ++a) accs[a] = make_float2(0.f, 0.f);
    int count = 0;

    #pragma unroll
    for (int k = 0; k < NCHUNK; ++k) {
        const int b = k & 1;
        const int m = nm[k];          // written by classify in iter k-1
        count += m;

        // ---- Gather chunk k: pad-to-8 with rows[b][0] (L1-hot duplicate),
        // 8 static independent float2 loads per burst (16 VGPRs in flight).
        const int mp = (m + 7) & ~7;
        for (int j = 0; j < mp; j += 8) {
            float2 v[8];
            #pragma unroll
            for (int u = 0; u < 8; ++u) {
                const int jj = j + u;
                const int r = rows[b][jj < m ? jj : 0];  // LDS broadcast
                v[u] = *reinterpret_cast<const float2*>(
                    embed + (size_t)r * EMBED_DIM + d0);
            }
            #pragma unroll
            for (int u = 0; u < 8; ++u) {
                accs[u & 3].x += v[u].x;
                accs[u & 3].y += v[u].y;
            }
        }
        if (mp > m) {                 // remove pad contribution (L1 hit)
            const float pad = (float)(mp - m);
            const int r0 = rows[b][0];
            const float2 v0 = *reinterpret_cast<const float2*>(
                embed + (size_t)r0 * EMBED_DIM + d0);
            accs[0].x = fmaf(-pad, v0.x, accs[0].x);
            accs[0].y = fmaf(-pad, v0.y, accs[0].y);
        }

        // ---- Classify chunk k+1 from STAGED registers (y latency already
        // hidden under the gather above) into the other buffer.
        if (k + 1 < NCHUNK) {
            const int base_ = (k + 1) * CHUNK + tid * 4;
#define CLS(yv, q)                                                          \
            {                                                               \
                const int i0 = base_ + (q) * 1024;                          \
                if (yv.x == c) { int p = atomicAdd(&nm[k + 1], 1); rows[b ^ 1][p] = i0 + 0; } \
                if (yv.y == c) { int p = atomicAdd(&nm[k + 1], 1); rows[b ^ 1][p] = i0 + 1; } \
                if (yv.z == c) { int p = atomicAdd(&nm[k + 1], 1); rows[b ^ 1][p] = i0 + 2; } \
                if (yv.w == c) { int p = atomicAdd(&nm[k + 1], 1); rows[b ^ 1][p] = i0 + 3; } \
            }
            CLS(yv0, 0) CLS(yv1, 1) CLS(yv2, 2) CLS(yv3, 3)
#undef CLS
        }
        // ---- Stage chunk k+2's labels (consumed next iteration, after the
        // next gather — a full gather phase of latency headroom).
        if (k + 2 < NCHUNK) {
            const int base_ = (k + 2) * CHUNK + tid * 4;
            yv0 = *reinterpret_cast<const int4*>(y + base_ + 0 * 1024);
            yv1 = *reinterpret_cast<const int4*>(y + base_ + 1 * 1024);
            yv2 = *reinterpret_cast<const int4*>(y + base_ + 2 * 1024);
            yv3 = *reinterpret_cast<const int4*>(y + base_ + 3 * 1024);
        }
        __syncthreads();              // one barrier per chunk
    }

    // ---- Epilogue: mean, blend, store. count==0 -> 0*inf = NaN (matches ref).
    const float inv = 1.0f / (float)count;
    const float sx = (accs[0].x + accs[1].x) + (accs[2].x + accs[3].x);
    const float sy = (accs[0].y + accs[1].y) + (accs[2].y + accs[3].y);
    float2 res;
    res.x = FACTOR * (sx * inv) + (1.0f - FACTOR) * cen.x;
    res.y = FACTOR * (sy * inv) + (1.0f - FACTOR) * cen.y;
    *reinterpret_cast<float2*>(out + o) = res;
}

extern "C" void kernel_launch(void* const* d_in, const int* in_sizes, int n_in,
                              void* d_out, int out_size, void* d_ws, size_t ws_size,
                              hipStream_t stream) {
    const float* embed    = (const float*)d_in[0];  // [32768, 1024]
    const int*   y        = (const int*)d_in[1];    // [32768] int32
    const float* centroid = (const float*)d_in[2];  // [1000, 1024]
    float*       out      = (float*)d_out;          // [1000, 1024]

    centroid_kernel<<<NUM_CLASSES * 2, 256, 0, stream>>>(embed, y, centroid, out);
}

// Round 10
// 201.723 us; speedup vs baseline: 1.0251x; 1.0251x over previous
//
#include <hip/hip_runtime.h>

// Centroid update: per-class mean of embed rows, blended with old centroid.
//   sums[c,:] = sum_{i: y[i]==c} embed[i,:]
//   out[c,:]  = 0.3 * sums[c,:]/count[c] + 0.7 * centroid[c,:]
//
// v10 = v8 verbatim (201.2 µs, best of 10 variants). v9's classify-late
// restructure regressed (+5.6 µs): it moved the serial compare/LDS-atomic
// chain from "overlapped with the gather's vmcnt waits" to "directly before
// the barrier", lengthening the per-chunk critical path. Reverted.
//
// The three counter-backed levers this kernel combines:
//  * INTERLEAVE scan and gather (v0 evidence): per-chunk (4096 labels) scan
//    of chunk k+1 overlaps the gather of chunk k via double-buffered row
//    lists; ONE barrier per chunk (8 total).
//  * Occupancy (v6 evidence: 9%->36% occ doubled delivered BW): 2000 blocks
//    (class x dim-half, float2/thread) -> 7.8 blk/CU, ~31 waves/CU ceiling.
//  * Register-sized bursts (v6's spill disaster, v7's no-spill): pad-to-4
//    static float2 bursts = 8 VGPRs in flight, no scratch traffic.
// Remaining window: ~156 µs of harness poison fills (2 x 512 MiB @ 86%
// peak, serialized with our kernel in the capture graph) + ~45 µs kernel.

#define BATCH       32768
#define EMBED_DIM   1024
#define NUM_CLASSES 1000
#define FACTOR      0.3f
#define HALF_DIM    512
#define CHUNK       4096   // labels per chunk; 8 chunks of 4 int4 per thread
#define NCHUNK      (BATCH / CHUNK)
#define MAXR        80     // per-chunk matches: Poisson(4.1), max ~20; 80 safe

__global__ __launch_bounds__(256) void centroid_kernel(
    const float* __restrict__ embed,
    const int*   __restrict__ y,
    const float* __restrict__ centroid,
    float*       __restrict__ out)
{
    const int bid = blockIdx.x;
    const int c   = bid >> 1;                 // class
    const int h   = bid & 1;                  // dim half
    const int tid = threadIdx.x;
    const int d0  = h * HALF_DIM + tid * 2;   // this thread's 2 dims

    __shared__ int rows[2][MAXR];             // double-buffered match lists
    __shared__ int nm[2];

    if (tid < 2) nm[tid] = 0;

    // Hoisted: centroid load overlaps everything.
    const size_t o = (size_t)c * EMBED_DIM + d0;
    const float2 cen = *reinterpret_cast<const float2*>(centroid + o);

    __syncthreads();

    // Scan one 4096-label chunk into buffer b. 4 coalesced int4 loads per
    // thread, independent -> pipelined. y is 128 KB, L2-resident.
#define SCAN(ck, b)                                                         \
    {                                                                       \
        const int base_ = (ck) * CHUNK + tid * 4;                           \
        _Pragma("unroll")                                                   \
        for (int q = 0; q < 4; ++q) {                                       \
            const int idx = base_ + q * 1024;                               \
            const int4 v = *reinterpret_cast<const int4*>(y + idx);         \
            if (v.x == c) { int p = atomicAdd(&nm[b], 1); rows[b][p] = idx + 0; } \
            if (v.y == c) { int p = atomicAdd(&nm[b], 1); rows[b][p] = idx + 1; } \
            if (v.z == c) { int p = atomicAdd(&nm[b], 1); rows[b][p] = idx + 2; } \
            if (v.w == c) { int p = atomicAdd(&nm[b], 1); rows[b][p] = idx + 3; } \
        }                                                                   \
    }

    // Prologue: fill buffer 0.
    SCAN(0, 0)
    __syncthreads();

    float2 acc0 = make_float2(0.f, 0.f);
    float2 acc1 = make_float2(0.f, 0.f);
    int count = 0;

    for (int k = 0; k < NCHUNK; ++k) {
        const int b = k & 1;
        const int m = nm[b];          // block-uniform, read before reset

        // Issue next chunk's scan first: its y-loads + LDS atomics target
        // the OTHER buffer and overlap the gather's global loads below.
        if (k + 1 < NCHUNK) SCAN(k + 1, b ^ 1)

        // Gather buffer b: pad to multiple of 4 with rows[b][0] (L1-hot
        // duplicate line), static 4-deep float2 bursts = 8 VGPRs in flight.
        const int mp = (m + 3) & ~3;
        for (int j = 0; j < mp; j += 4) {
            float2 v[4];
            #pragma unroll
            for (int u = 0; u < 4; ++u) {
                const int jj = j + u;
                const int r = rows[b][jj < m ? jj : 0];  // LDS broadcast
                v[u] = *reinterpret_cast<const float2*>(
                    embed + (size_t)r * EMBED_DIM + d0);
            }
            acc0.x += v[0].x; acc0.y += v[0].y;
            acc1.x += v[1].x; acc1.y += v[1].y;
            acc0.x += v[2].x; acc0.y += v[2].y;
            acc1.x += v[3].x; acc1.y += v[3].y;
        }
        // Remove pad contribution ((mp-m) copies of rows[b][0], L1 hit).
        if (mp > m) {
            const float pad = (float)(mp - m);
            const int r0 = rows[b][0];
            const float2 v0 = *reinterpret_cast<const float2*>(
                embed + (size_t)r0 * EMBED_DIM + d0);
            acc0.x = fmaf(-pad, v0.x, acc0.x);
            acc0.y = fmaf(-pad, v0.y, acc0.y);
        }
        count += m;

        if (tid == 0) nm[b] = 0;      // ready for chunk k+2
        __syncthreads();              // one barrier per chunk
    }

    // ---- Epilogue: mean, blend, store. count==0 -> 0*inf = NaN (matches ref).
    const float inv = 1.0f / (float)count;
    const float sx = acc0.x + acc1.x;
    const float sy = acc0.y + acc1.y;
    float2 res;
    res.x = FACTOR * (sx * inv) + (1.0f - FACTOR) * cen.x;
    res.y = FACTOR * (sy * inv) + (1.0f - FACTOR) * cen.y;
    *reinterpret_cast<float2*>(out + o) = res;
#undef SCAN
}

extern "C" void kernel_launch(void* const* d_in, const int* in_sizes, int n_in,
                              void* d_out, int out_size, void* d_ws, size_t ws_size,
                              hipStream_t stream) {
    const float* embed    = (const float*)d_in[0];  // [32768, 1024]
    const int*   y        = (const int*)d_in[1];    // [32768] int32
    const float* centroid = (const float*)d_in[2];  // [1000, 1024]
    float*       out      = (float*)d_out;          // [1000, 1024]

    centroid_kernel<<<NUM_CLASSES * 2, 256, 0, stream>>>(embed, y, centroid, out);
}